// Round 2
// baseline (1854.423 us; speedup 1.0000x reference)
//
#include <hip/hip_runtime.h>
#include <hip/hip_bf16.h>

// Scatter-add rows of X (features F = F4*4 floats) from src nodes into agg at dst nodes.
// One thread per (edge, float4-chunk). Edge indices are int32 (harness converts int64 -> int).
__global__ void scatter_add_f4(const float4* __restrict__ xf4,
                               const int* __restrict__ idx,
                               float* __restrict__ agg, int E, int F4) {
    int gid = blockIdx.x * blockDim.x + threadIdx.x;
    int e = gid / F4;
    if (e >= E) return;
    int q = gid - e * F4;
    int s = idx[e];        // src
    int d = idx[E + e];    // dst
    float4 v = xf4[(long)s * F4 + q];
    float* p = agg + (long)d * (F4 * 4) + q * 4;
    atomicAdd(p + 0, v.x);
    atomicAdd(p + 1, v.y);
    atomicAdd(p + 2, v.z);
    atomicAdd(p + 3, v.w);
}

// H[r,j] = relu(sum_k A[r,k]*W[k,j] + b[j]);  A: [N,96], W: [96,64] row-major, H: [N,64]
// 64 threads per row (one per output col), 4 rows per 256-thread block.
__global__ void gemm96x64_relu(const float* __restrict__ A,
                               const float* __restrict__ W,
                               const float* __restrict__ b,
                               float* __restrict__ H, int N) {
    int r = blockIdx.x * 4 + (threadIdx.x >> 6);
    int j = threadIdx.x & 63;
    if (r >= N) return;
    const float* a = A + (long)r * 96;
    float acc = b[j];
#pragma unroll
    for (int k = 0; k < 96; ++k) acc = fmaf(a[k], W[k * 64 + j], acc);
    H[(long)r * 64 + j] = fmaxf(acc, 0.f);
}

// out[r,:] = log_softmax(A[r,:] @ W + b);  A: [N,64], W: [64,32], out: [N,32]
// 32 threads per row, 8 rows per 256-thread block. Shuffle-reduce within 32-lane groups.
__global__ void gemm64x32_lsm(const float* __restrict__ A,
                              const float* __restrict__ W,
                              const float* __restrict__ b,
                              float* __restrict__ out, int N) {
    int r = blockIdx.x * 8 + (threadIdx.x >> 5);
    int j = threadIdx.x & 31;
    if (r >= N) return;
    const float* a = A + (long)r * 64;
    float acc = b[j];
#pragma unroll
    for (int k = 0; k < 64; ++k) acc = fmaf(a[k], W[k * 32 + j], acc);
    // max over the 32-lane group
    float m = acc;
#pragma unroll
    for (int o = 16; o > 0; o >>= 1) m = fmaxf(m, __shfl_xor(m, o, 32));
    float ex = __expf(acc - m);
    float s = ex;
#pragma unroll
    for (int o = 16; o > 0; o >>= 1) s += __shfl_xor(s, o, 32);
    out[(long)r * 32 + j] = acc - m - __logf(s);
}

extern "C" void kernel_launch(void* const* d_in, const int* in_sizes, int n_in,
                              void* d_out, int out_size, void* d_ws, size_t ws_size,
                              hipStream_t stream) {
    const float* x  = (const float*)d_in[0];      // [N,96]
    const int*   ei = (const int*)d_in[1];        // [2,E] (int64 in ref -> int32 on device)
    const float* W1 = (const float*)d_in[2];      // [96,64]
    const float* b1 = (const float*)d_in[3];      // [64]
    const float* W2 = (const float*)d_in[4];      // [64,32]
    const float* b2 = (const float*)d_in[5];      // [32]
    float* out = (float*)d_out;                   // [N,32]

    const int N = in_sizes[0] / 96;
    const int E = in_sizes[1] / 2;

    float* agg1 = (float*)d_ws;                 // [N,96] = 19.2 MB
    float* h    = agg1 + (size_t)N * 96;        // [N,64] = 12.8 MB
    float* agg2 = agg1;                         // reuse agg1 slot ([N,64] fits)

    // Layer 1: agg1 = A * x  (scatter-add), h = relu(agg1 @ W1 + b1)
    hipMemsetAsync(agg1, 0, (size_t)N * 96 * sizeof(float), stream);
    {
        long threads = (long)E * 24;  // 24 float4 chunks per 96-float row
        int grid = (int)((threads + 255) / 256);
        scatter_add_f4<<<grid, 256, 0, stream>>>((const float4*)x, ei, agg1, E, 24);
    }
    gemm96x64_relu<<<(N + 3) / 4, 256, 0, stream>>>(agg1, W1, b1, h, N);

    // Layer 2: agg2 = A * h, out = log_softmax(agg2 @ W2 + b2)
    hipMemsetAsync(agg2, 0, (size_t)N * 64 * sizeof(float), stream);
    {
        long threads = (long)E * 16;  // 16 float4 chunks per 64-float row
        int grid = (int)((threads + 255) / 256);
        scatter_add_f4<<<grid, 256, 0, stream>>>((const float4*)h, ei, agg2, E, 16);
    }
    gemm64x32_lsm<<<(N + 7) / 8, 256, 0, stream>>>(agg2, W2, b2, out, N);
}

// Round 3
// 351.195 us; speedup vs baseline: 5.2803x; 5.2803x over previous
//
#include <hip/hip_runtime.h>
#include <hip/hip_bf16.h>

// ---------------- CSR build (counting sort by dst) ----------------

__global__ void hist_dst(const int* __restrict__ ei, int* __restrict__ cnt, int E) {
    int e = blockIdx.x * blockDim.x + threadIdx.x;
    if (e >= E) return;
    atomicAdd(&cnt[ei[E + e]], 1);
}

// Per-256-block exclusive scan; emits block sums.
__global__ void scan256(const int* __restrict__ in, int* __restrict__ out,
                        int* __restrict__ blksum, int N) {
    __shared__ int lds[256];
    int i = blockIdx.x * 256 + threadIdx.x;
    int v = (i < N) ? in[i] : 0;
    lds[threadIdx.x] = v;
    __syncthreads();
    for (int off = 1; off < 256; off <<= 1) {
        int t = (threadIdx.x >= off) ? lds[threadIdx.x - off] : 0;
        __syncthreads();
        lds[threadIdx.x] += t;
        __syncthreads();
    }
    if (i < N) out[i] = lds[threadIdx.x] - v;  // exclusive
    if (threadIdx.x == 255) blksum[blockIdx.x] = lds[255];
}

// Single-block exclusive scan of block sums (nb <= 1024).
__global__ void scan_blk(int* __restrict__ blksum, int nb) {
    __shared__ int lds[1024];
    int i = threadIdx.x;
    int v = (i < nb) ? blksum[i] : 0;
    lds[i] = v;
    __syncthreads();
    for (int off = 1; off < 1024; off <<= 1) {
        int t = (i >= off) ? lds[i - off] : 0;
        __syncthreads();
        lds[i] += t;
        __syncthreads();
    }
    if (i < nb) blksum[i] = lds[i] - v;
}

// Add block bases; write final offsets into offs and cursor; offs[N] = E.
__global__ void scan_fix(int* __restrict__ offs, int* __restrict__ cursor,
                         const int* __restrict__ blksum, int N, int E) {
    int i = blockIdx.x * 256 + threadIdx.x;
    if (i < N) {
        int v = offs[i] + blksum[i >> 8];
        offs[i] = v;
        cursor[i] = v;
    }
    if (i == N) offs[N] = E;
}

__global__ void reorder(const int* __restrict__ ei, int* __restrict__ cursor,
                        int* __restrict__ srcs, int E) {
    int e = blockIdx.x * blockDim.x + threadIdx.x;
    if (e >= E) return;
    int d = ei[E + e];
    int pos = atomicAdd(&cursor[d], 1);
    srcs[pos] = ei[e];
}

// ---------------- Gather aggregation (no fp32 atomics) ----------------
// Thread = (node, float4 chunk). agg[n] = sum over edge bucket of x[src].
__global__ void gather_agg(const float4* __restrict__ xf4, const int* __restrict__ offs,
                           const int* __restrict__ srcs, float4* __restrict__ agg,
                           int N, int F4) {
    int gid = blockIdx.x * blockDim.x + threadIdx.x;
    int n = gid / F4;
    if (n >= N) return;
    int q = gid - n * F4;
    int s0 = offs[n], s1 = offs[n + 1];
    float4 acc = make_float4(0.f, 0.f, 0.f, 0.f);
    for (int e = s0; e < s1; ++e) {
        int s = srcs[e];
        float4 v = xf4[(long)s * F4 + q];
        acc.x += v.x; acc.y += v.y; acc.z += v.z; acc.w += v.w;
    }
    agg[(long)n * F4 + q] = acc;
}

// ---------------- Fallback scatter (fp32 atomics) ----------------
__global__ void scatter_add_f4(const float4* __restrict__ xf4, const int* __restrict__ idx,
                               float* __restrict__ agg, int E, int F4) {
    int gid = blockIdx.x * blockDim.x + threadIdx.x;
    int e = gid / F4;
    if (e >= E) return;
    int q = gid - e * F4;
    int s = idx[e];
    int d = idx[E + e];
    float4 v = xf4[(long)s * F4 + q];
    float* p = agg + (long)d * (F4 * 4) + q * 4;
    atomicAdd(p + 0, v.x);
    atomicAdd(p + 1, v.y);
    atomicAdd(p + 2, v.z);
    atomicAdd(p + 3, v.w);
}

// ---------------- Dense layers ----------------
__global__ void gemm96x64_relu(const float* __restrict__ A, const float* __restrict__ W,
                               const float* __restrict__ b, float* __restrict__ H, int N) {
    int r = blockIdx.x * 4 + (threadIdx.x >> 6);
    int j = threadIdx.x & 63;
    if (r >= N) return;
    const float* a = A + (long)r * 96;
    float acc = b[j];
#pragma unroll
    for (int k = 0; k < 96; ++k) acc = fmaf(a[k], W[k * 64 + j], acc);
    H[(long)r * 64 + j] = fmaxf(acc, 0.f);
}

__global__ void gemm64x32_lsm(const float* __restrict__ A, const float* __restrict__ W,
                              const float* __restrict__ b, float* __restrict__ out, int N) {
    int r = blockIdx.x * 8 + (threadIdx.x >> 5);
    int j = threadIdx.x & 31;
    if (r >= N) return;
    const float* a = A + (long)r * 64;
    float acc = b[j];
#pragma unroll
    for (int k = 0; k < 64; ++k) acc = fmaf(a[k], W[k * 32 + j], acc);
    float m = acc;
#pragma unroll
    for (int o = 16; o > 0; o >>= 1) m = fmaxf(m, __shfl_xor(m, o, 32));
    float ex = __expf(acc - m);
    float s = ex;
#pragma unroll
    for (int o = 16; o > 0; o >>= 1) s += __shfl_xor(s, o, 32);
    out[(long)r * 32 + j] = acc - m - __logf(s);
}

extern "C" void kernel_launch(void* const* d_in, const int* in_sizes, int n_in,
                              void* d_out, int out_size, void* d_ws, size_t ws_size,
                              hipStream_t stream) {
    const float* x  = (const float*)d_in[0];      // [N,96]
    const int*   ei = (const int*)d_in[1];        // [2,E] (int64 -> int32 on device)
    const float* W1 = (const float*)d_in[2];      // [96,64]
    const float* b1 = (const float*)d_in[3];      // [64]
    const float* W2 = (const float*)d_in[4];      // [64,32]
    const float* b2 = (const float*)d_in[5];      // [32]
    float* out = (float*)d_out;                   // [N,32]

    const int N = in_sizes[0] / 96;
    const int E = in_sizes[1] / 2;

    float* agg1 = (float*)d_ws;                  // [N,96]
    float* h    = agg1 + (size_t)N * 96;         // [N,64]
    float* agg2 = agg1;                          // reuse

    size_t base_floats = (size_t)N * 96 + (size_t)N * 64;
    int* offs   = (int*)(h + (size_t)N * 64);    // [N+1]
    int* cursor = offs + (N + 1);                // [N]
    int* blksum = cursor + N;                    // [<=1024]
    int* srcs   = blksum + 1024;                 // [E]
    size_t need = base_floats * 4 + ((size_t)(N + 1) + N + 1024 + E) * 4;

    if (ws_size >= need) {
        // --- Build CSR by dst (counting sort) ---
        int nb = (N + 255) / 256;
        hipMemsetAsync(offs, 0, (size_t)N * sizeof(int), stream);   // use offs as cnt first
        hist_dst<<<(E + 255) / 256, 256, 0, stream>>>(ei, offs, E);
        // scan256 reads cnt in offs, writes exclusive partials in place?  Need separate
        // in/out: use cursor as the partial output, then fix into offs+cursor.
        scan256<<<nb, 256, 0, stream>>>(offs, cursor, blksum, N);
        scan_blk<<<1, 1024, 0, stream>>>(blksum, nb);
        // cursor currently holds per-block exclusive partials; move to offs with base add
        // scan_fix reads partials from 'offs' param: pass cursor as offs-source.
        // To keep it simple: scan_fix(offs=cursor?) -> write final into offs and cursor.
        scan_fix<<<(N + 256) / 256, 256, 0, stream>>>(cursor, cursor, blksum, N, E);
        // now cursor holds final offsets; copy into offs (need both: offs stable + cursor mutable)
        hipMemcpyAsync(offs, cursor, (size_t)N * sizeof(int), hipMemcpyDeviceToDevice, stream);
        // offs[N] = E was written only if i==N hit in scan_fix's index space (it does: grid covers N+1... 
        // scan_fix wrote cursor[N]? No: it writes offs[N]=E where 'offs' param == cursor, so cursor[N]=E.
        // But cursor has only N slots... blksum sits right after. Guard: write offs[N] via memcpy below.
        hipMemcpyAsync(offs + N, cursor + N, sizeof(int), hipMemcpyDeviceToDevice, stream);
        reorder<<<(E + 255) / 256, 256, 0, stream>>>(ei, cursor, srcs, E);

        // --- Layer 1 ---
        {
            long t = (long)N * 24;
            gather_agg<<<(int)((t + 255) / 256), 256, 0, stream>>>(
                (const float4*)x, offs, srcs, (float4*)agg1, N, 24);
        }
        gemm96x64_relu<<<(N + 3) / 4, 256, 0, stream>>>(agg1, W1, b1, h, N);
        // --- Layer 2 ---
        {
            long t = (long)N * 16;
            gather_agg<<<(int)((t + 255) / 256), 256, 0, stream>>>(
                (const float4*)h, offs, srcs, (float4*)agg2, N, 16);
        }
        gemm64x32_lsm<<<(N + 7) / 8, 256, 0, stream>>>(agg2, W2, b2, out, N);
    } else {
        // --- Fallback: atomic scatter path (round-2 version) ---
        hipMemsetAsync(agg1, 0, (size_t)N * 96 * sizeof(float), stream);
        {
            long t = (long)E * 24;
            scatter_add_f4<<<(int)((t + 255) / 256), 256, 0, stream>>>(
                (const float4*)x, ei, agg1, E, 24);
        }
        gemm96x64_relu<<<(N + 3) / 4, 256, 0, stream>>>(agg1, W1, b1, h, N);
        hipMemsetAsync(agg2, 0, (size_t)N * 64 * sizeof(float), stream);
        {
            long t = (long)E * 16;
            scatter_add_f4<<<(int)((t + 255) / 256), 256, 0, stream>>>(
                (const float4*)h, ei, agg2, E, 16);
        }
        gemm64x32_lsm<<<(N + 7) / 8, 256, 0, stream>>>(agg2, W2, b2, out, N);
    }
}

// Round 4
// 259.726 us; speedup vs baseline: 7.1399x; 1.3522x over previous
//
#include <hip/hip_runtime.h>
#include <hip/hip_bf16.h>

typedef __attribute__((ext_vector_type(8))) short bf16x8;
typedef __attribute__((ext_vector_type(4))) float f32x4;

__device__ inline unsigned short f2bf(float f) {
    unsigned u = __float_as_uint(f);
    return (unsigned short)((u + 0x7fffu + ((u >> 16) & 1u)) >> 16);
}
__device__ inline unsigned pack2(float a, float b) {
    return (unsigned)f2bf(a) | ((unsigned)f2bf(b) << 16);
}
__device__ inline float blo(unsigned u) { return __uint_as_float(u << 16); }
__device__ inline float bhi(unsigned u) { return __uint_as_float(u & 0xffff0000u); }

// ---------------- casts ----------------
// 8 floats -> 8 bf16 per thread
__global__ void cast_f32_bf16(const float4* __restrict__ in, uint4* __restrict__ out, int n8) {
    int i = blockIdx.x * blockDim.x + threadIdx.x;
    if (i >= n8) return;
    float4 a = in[i * 2], b = in[i * 2 + 1];
    uint4 o;
    o.x = pack2(a.x, a.y); o.y = pack2(a.z, a.w);
    o.z = pack2(b.x, b.y); o.w = pack2(b.z, b.w);
    out[i] = o;
}

// W[K][Nc] fp32 -> Wt[Nc][K] bf16
__global__ void cast_wt(const float* __restrict__ W, unsigned short* __restrict__ Wt,
                        int K, int Nc) {
    int idx = blockIdx.x * blockDim.x + threadIdx.x;
    if (idx >= K * Nc) return;
    int n = idx / K;
    int k = idx - n * K;
    Wt[idx] = f2bf(W[k * Nc + n]);
}

// ---------------- CSR build (counting sort by dst) ----------------
__global__ void hist_dst(const int* __restrict__ ei, int* __restrict__ cnt, int E) {
    int e = blockIdx.x * blockDim.x + threadIdx.x;
    if (e >= E) return;
    atomicAdd(&cnt[ei[E + e]], 1);
}

__global__ void scan256(const int* __restrict__ in, int* __restrict__ out,
                        int* __restrict__ blksum, int N) {
    __shared__ int lds[256];
    int i = blockIdx.x * 256 + threadIdx.x;
    int v = (i < N) ? in[i] : 0;
    lds[threadIdx.x] = v;
    __syncthreads();
    for (int off = 1; off < 256; off <<= 1) {
        int t = (threadIdx.x >= off) ? lds[threadIdx.x - off] : 0;
        __syncthreads();
        lds[threadIdx.x] += t;
        __syncthreads();
    }
    if (i < N) out[i] = lds[threadIdx.x] - v;  // exclusive
    if (threadIdx.x == 255) blksum[blockIdx.x] = lds[255];
}

__global__ void scan_blk(int* __restrict__ blksum, int nb) {
    __shared__ int lds[1024];
    int i = threadIdx.x;
    int v = (i < nb) ? blksum[i] : 0;
    lds[i] = v;
    __syncthreads();
    for (int off = 1; off < 1024; off <<= 1) {
        int t = (i >= off) ? lds[i - off] : 0;
        __syncthreads();
        lds[i] += t;
        __syncthreads();
    }
    if (i < nb) blksum[i] = lds[i] - v;
}

// offs[i] += block base; cursor[i] = offs[i]; offs[N] = E.
__global__ void scan_fix(int* __restrict__ offs, int* __restrict__ cursor,
                         const int* __restrict__ blksum, int N, int E) {
    int i = blockIdx.x * 256 + threadIdx.x;
    if (i < N) {
        int v = offs[i] + blksum[i >> 8];
        offs[i] = v;
        cursor[i] = v;
    }
    if (i == N) offs[N] = E;
}

__global__ void reorder(const int* __restrict__ ei, int* __restrict__ cursor,
                        int* __restrict__ srcs, int E) {
    int e = blockIdx.x * blockDim.x + threadIdx.x;
    if (e >= E) return;
    int d = ei[E + e];
    int pos = atomicAdd(&cursor[d], 1);
    srcs[pos] = ei[e];
}

// ---------------- gather aggregation, bf16 in / bf16 out ----------------
// Thread = (node, 16B chunk of 8 bf16). C = chunks per row (12 for 96f, 8 for 64f).
__global__ void gather_agg_bf16(const uint4* __restrict__ xb, const int* __restrict__ offs,
                                const int* __restrict__ srcs, uint4* __restrict__ agg,
                                int N, int C) {
    int gid = blockIdx.x * blockDim.x + threadIdx.x;
    int n = gid / C;
    if (n >= N) return;
    int q = gid - n * C;
    int s0 = offs[n], s1 = offs[n + 1];
    float a0 = 0, a1 = 0, a2 = 0, a3 = 0, a4 = 0, a5 = 0, a6 = 0, a7 = 0;
    for (int e = s0; e < s1; ++e) {
        uint4 v = xb[(long)srcs[e] * C + q];
        a0 += blo(v.x); a1 += bhi(v.x);
        a2 += blo(v.y); a3 += bhi(v.y);
        a4 += blo(v.z); a5 += bhi(v.z);
        a6 += blo(v.w); a7 += bhi(v.w);
    }
    uint4 o;
    o.x = pack2(a0, a1); o.y = pack2(a2, a3);
    o.z = pack2(a4, a5); o.w = pack2(a6, a7);
    agg[(long)n * C + q] = o;
}

// ---------------- MFMA GEMMs ----------------
// h = relu(A @ W1 + b1); A: [M][96] bf16, Bt: [64][96] bf16 (n-major), H: [M][64] bf16.
// One wave per 16-row tile; 4 n-tiles x 3 k-steps of 16x16x32.
__global__ void mfma_gemm1_relu(const unsigned short* __restrict__ A,
                                const unsigned short* __restrict__ Bt,
                                const float* __restrict__ bias,
                                unsigned short* __restrict__ H, int Mtiles) {
    int wave = blockIdx.x * 4 + (threadIdx.x >> 6);
    if (wave >= Mtiles) return;
    int lane = threadIdx.x & 63;
    int l15 = lane & 15, quad = lane >> 4;
    const int K = 96;
    long arow = (long)(wave * 16 + l15) * K + quad * 8;
    f32x4 acc[4] = {{0,0,0,0},{0,0,0,0},{0,0,0,0},{0,0,0,0}};
#pragma unroll
    for (int t = 0; t < 3; ++t) {
        bf16x8 af = *(const bf16x8*)(A + arow + t * 32);
#pragma unroll
        for (int nt = 0; nt < 4; ++nt) {
            bf16x8 bfr = *(const bf16x8*)(Bt + (long)(nt * 16 + l15) * K + t * 32 + quad * 8);
            acc[nt] = __builtin_amdgcn_mfma_f32_16x16x32_bf16(af, bfr, acc[nt], 0, 0, 0);
        }
    }
    int mbase = wave * 16 + quad * 4;  // C/D: row = quad*4 + reg, col = l15 (m89-verified)
#pragma unroll
    for (int nt = 0; nt < 4; ++nt) {
        int col = nt * 16 + l15;
        float bb = bias[col];
#pragma unroll
        for (int r = 0; r < 4; ++r) {
            float v = fmaxf(acc[nt][r] + bb, 0.f);
            H[(long)(mbase + r) * 64 + col] = f2bf(v);
        }
    }
}

// out = log_softmax(A @ W2 + b2); A: [M][64] bf16, Bt: [32][64] bf16, out: [M][32] fp32.
__global__ void mfma_gemm2_lsm(const unsigned short* __restrict__ A,
                               const unsigned short* __restrict__ Bt,
                               const float* __restrict__ bias,
                               float* __restrict__ out, int Mtiles) {
    int wave = blockIdx.x * 4 + (threadIdx.x >> 6);
    if (wave >= Mtiles) return;
    int lane = threadIdx.x & 63;
    int l15 = lane & 15, quad = lane >> 4;
    const int K = 64;
    long arow = (long)(wave * 16 + l15) * K + quad * 8;
    f32x4 acc[2] = {{0,0,0,0},{0,0,0,0}};
#pragma unroll
    for (int t = 0; t < 2; ++t) {
        bf16x8 af = *(const bf16x8*)(A + arow + t * 32);
#pragma unroll
        for (int nt = 0; nt < 2; ++nt) {
            bf16x8 bfr = *(const bf16x8*)(Bt + (long)(nt * 16 + l15) * K + t * 32 + quad * 8);
            acc[nt] = __builtin_amdgcn_mfma_f32_16x16x32_bf16(af, bfr, acc[nt], 0, 0, 0);
        }
    }
    float b0 = bias[l15], b16 = bias[16 + l15];
    int mbase = wave * 16 + quad * 4;
#pragma unroll
    for (int r = 0; r < 4; ++r) {
        float v0 = acc[0][r] + b0;
        float v1 = acc[1][r] + b16;
        // row r's 32 cols live in the 16 lanes sharing this quad
        float m = fmaxf(v0, v1);
#pragma unroll
        for (int o = 1; o < 16; o <<= 1) m = fmaxf(m, __shfl_xor(m, o));
        float s = __expf(v0 - m) + __expf(v1 - m);
#pragma unroll
        for (int o = 1; o < 16; o <<= 1) s += __shfl_xor(s, o);
        float ls = __logf(s);
        long rb = (long)(mbase + r) * 32;
        out[rb + l15] = v0 - m - ls;
        out[rb + 16 + l15] = v1 - m - ls;
    }
}

extern "C" void kernel_launch(void* const* d_in, const int* in_sizes, int n_in,
                              void* d_out, int out_size, void* d_ws, size_t ws_size,
                              hipStream_t stream) {
    const float* x  = (const float*)d_in[0];      // [N,96]
    const int*   ei = (const int*)d_in[1];        // [2,E] (int64 -> int32 on device)
    const float* W1 = (const float*)d_in[2];      // [96,64]
    const float* b1 = (const float*)d_in[3];      // [64]
    const float* W2 = (const float*)d_in[4];      // [64,32]
    const float* b2 = (const float*)d_in[5];      // [32]
    float* out = (float*)d_out;                   // [N,32]

    const int N = in_sizes[0] / 96;
    const int E = in_sizes[1] / 2;

    // ws layout (all 16B-aligned)
    char* p = (char*)d_ws;
    unsigned short* aggb = (unsigned short*)p;            p += (size_t)N * 96 * 2;  // agg1 [N][96] / agg2 [N][64]
    unsigned short* hb   = (unsigned short*)p;            p += (size_t)N * 64 * 2;  // h [N][64]
    unsigned short* xb   = (unsigned short*)p;            p += (size_t)N * 96 * 2;  // x bf16
    unsigned short* w1t  = (unsigned short*)p;            p += 96 * 64 * 2;         // [64][96]
    unsigned short* w2t  = (unsigned short*)p;            p += 64 * 32 * 2;         // [32][64]
    int* offs   = (int*)p;                                p += (size_t)(N + 1) * 4;
    int* cursor = (int*)p;                                p += (size_t)N * 4;
    int* blksum = (int*)p;                                p += 1024 * 4;
    int* srcs   = (int*)p;                                p += (size_t)E * 4;
    int* tmp    = (int*)p;                                p += (size_t)N * 4;

    // casts
    {
        int n8 = N * 96 / 8;
        cast_f32_bf16<<<(n8 + 255) / 256, 256, 0, stream>>>((const float4*)x, (uint4*)xb, n8);
        cast_wt<<<(96 * 64 + 255) / 256, 256, 0, stream>>>(W1, w1t, 96, 64);
        cast_wt<<<(64 * 32 + 255) / 256, 256, 0, stream>>>(W2, w2t, 64, 32);
    }

    // CSR build by dst
    int nb = (N + 255) / 256;
    hipMemsetAsync(tmp, 0, (size_t)N * sizeof(int), stream);
    hist_dst<<<(E + 255) / 256, 256, 0, stream>>>(ei, tmp, E);
    scan256<<<nb, 256, 0, stream>>>(tmp, offs, blksum, N);
    scan_blk<<<1, 1024, 0, stream>>>(blksum, nb);
    scan_fix<<<(N + 1 + 255) / 256, 256, 0, stream>>>(offs, cursor, blksum, N, E);
    reorder<<<(E + 255) / 256, 256, 0, stream>>>(ei, cursor, srcs, E);

    const int Mtiles = N / 16;  // 50000/16 = 3125 exactly

    // Layer 1
    {
        long t = (long)N * 12;
        gather_agg_bf16<<<(int)((t + 255) / 256), 256, 0, stream>>>(
            (const uint4*)xb, offs, srcs, (uint4*)aggb, N, 12);
    }
    mfma_gemm1_relu<<<(Mtiles + 3) / 4, 256, 0, stream>>>(aggb, w1t, b1, hb, Mtiles);

    // Layer 2 (agg2 reuses aggb slot)
    {
        long t = (long)N * 8;
        gather_agg_bf16<<<(int)((t + 255) / 256), 256, 0, stream>>>(
            (const uint4*)hb, offs, srcs, (uint4*)aggb, N, 8);
    }
    mfma_gemm2_lsm<<<(Mtiles + 3) / 4, 256, 0, stream>>>(aggb, w2t, b2, out, Mtiles);
}